// Round 1
// baseline (207.363 us; speedup 1.0000x reference)
//
#include <hip/hip_runtime.h>

// EXL2Linear — faithful to the reference's (quirky) unpack indexing:
// only W[:, 0:64] receives quantized codes; W[:, 64:] == qzero broadcast.
// out[r,o] = s0(o) * sum_{j<64} x[r,j]*uq(o,j) + sum_g qzero[o,g]*gsum[r,g] + bias[o]

constexpr int IFEAT  = 4096;
constexpr int OFEAT  = 4096;
constexpr int GROUPS = 32;   // IFEAT / 128
constexpr int KD     = 96;   // 64 quantized cols + 32 group sums

// ---------------- Kernel A: per-row x64 copy + group sums -> xg[rows][96]
__global__ __launch_bounds__(256) void prep_x_kernel(const float* __restrict__ x,
                                                     float* __restrict__ xg) {
    const int row  = blockIdx.x;
    const int t    = threadIdx.x;
    const int wave = t >> 6;
    const int lane = t & 63;
    const float* __restrict__ xr = x + (size_t)row * IFEAT;
    __shared__ float partial[16][4];

    // 16 chunks of 256 contiguous floats; each wave's 64 elems lie in one group
    for (int chunk = 0; chunk < 16; ++chunk) {
        float v = xr[chunk * 256 + t];
        #pragma unroll
        for (int off = 32; off > 0; off >>= 1) v += __shfl_xor(v, off);
        if (lane == 0) partial[chunk][wave] = v;
    }
    if (t < 64) xg[(size_t)row * KD + t] = xr[t];
    __syncthreads();
    if (t < GROUPS) {
        // group g covered by chunk g>>1, waves {2h, 2h+1} with h = g&1
        const int chunk = t >> 1;
        const int h     = t & 1;
        const float gs  = partial[chunk][2 * h] + partial[chunk][2 * h + 1];
        xg[(size_t)row * KD + 64 + t] = gs;
    }
}

// ---------------- Kernel B: build WeffT[96][OFEAT]
__global__ __launch_bounds__(256) void prep_w_kernel(const int* __restrict__ qweight,
                                                     const float* __restrict__ qscale,
                                                     const int* __restrict__ qzero,
                                                     float* __restrict__ weffT) {
    const int o = blockIdx.x * blockDim.x + threadIdx.x;
    if (o >= OFEAT) return;
    const float s0 = qscale[(size_t)o * GROUPS];  // group-0 scale
    const unsigned int* qw = (const unsigned int*)qweight + (size_t)o * (IFEAT / 8);
    unsigned int q[8];
    #pragma unroll
    for (int c = 0; c < 8; ++c) q[c] = qw[c];
    #pragma unroll
    for (int j = 0; j < 64; ++j) {
        const int c = j & 7;
        const int i = j >> 3;
        const float uq = (float)((q[c] >> (i * 4)) & 15u);
        weffT[(size_t)j * OFEAT + o] = uq * s0;
    }
    #pragma unroll
    for (int g = 0; g < GROUPS; ++g) {
        weffT[(size_t)(64 + g) * OFEAT + o] = (float)qzero[(size_t)o * GROUPS + g];
    }
}

// ---------------- Kernel C: out[rows][OFEAT] = xg @ WeffT + bias
// 64x64 tile per block, 4x4 register blocking, K=96 staged fully in LDS.
__global__ __launch_bounds__(256) void gemm96_kernel(const float* __restrict__ xg,
                                                     const float* __restrict__ weffT,
                                                     const float* __restrict__ bias,
                                                     float* __restrict__ out) {
    __shared__ float xs[KD][64];
    __shared__ float ws[KD][64];
    const int o0 = blockIdx.x * 64;
    const int r0 = blockIdx.y * 64;
    const int t  = threadIdx.x;

    // Stage xg tile (transpose [r][k] -> [k][r]); global reads coalesced.
    for (int idx = t; idx < KD * 64; idx += 256) {
        const int r = idx / KD;
        const int k = idx - r * KD;
        xs[k][r] = xg[(size_t)(r0 + r) * KD + k];
    }
    // Stage W tile; already [k][o] in global, fully coalesced.
    for (int idx = t; idx < KD * 64; idx += 256) {
        const int k = idx >> 6;
        const int c = idx & 63;
        ws[k][c] = weffT[(size_t)k * OFEAT + o0 + c];
    }
    __syncthreads();

    const int tr = t >> 4;   // 0..15 -> rows tr*4..tr*4+3
    const int tc = t & 15;   // 0..15 -> cols tc*4..tc*4+3
    float acc[4][4] = {};

    #pragma unroll
    for (int k = 0; k < KD; ++k) {
        const float4 a4 = *(const float4*)&xs[k][tr * 4];
        const float4 b4 = *(const float4*)&ws[k][tc * 4];
        const float a[4] = {a4.x, a4.y, a4.z, a4.w};
        const float b[4] = {b4.x, b4.y, b4.z, b4.w};
        #pragma unroll
        for (int i = 0; i < 4; ++i)
            #pragma unroll
            for (int j = 0; j < 4; ++j)
                acc[i][j] = fmaf(a[i], b[j], acc[i][j]);
    }

    const float4 bv = *(const float4*)&bias[o0 + tc * 4];
    const float bb[4] = {bv.x, bv.y, bv.z, bv.w};
    #pragma unroll
    for (int i = 0; i < 4; ++i) {
        const int r = r0 + tr * 4 + i;
        float4 ov;
        ov.x = acc[i][0] + bb[0];
        ov.y = acc[i][1] + bb[1];
        ov.z = acc[i][2] + bb[2];
        ov.w = acc[i][3] + bb[3];
        *(float4*)&out[(size_t)r * OFEAT + o0 + tc * 4] = ov;
    }
}

extern "C" void kernel_launch(void* const* d_in, const int* in_sizes, int n_in,
                              void* d_out, int out_size, void* d_ws, size_t ws_size,
                              hipStream_t stream) {
    const float* x       = (const float*)d_in[0];
    const int*   qweight = (const int*)d_in[1];
    const float* qscale  = (const float*)d_in[2];
    const int*   qzero   = (const int*)d_in[3];
    const float* bias    = (const float*)d_in[4];
    float*       out     = (float*)d_out;

    const int rows = in_sizes[0] / IFEAT;  // B*S = 8192

    float* xg    = (float*)d_ws;                       // rows*96 floats
    float* weffT = xg + (size_t)rows * KD;             // 96*OFEAT floats

    prep_x_kernel<<<rows, 256, 0, stream>>>(x, xg);
    prep_w_kernel<<<(OFEAT + 255) / 256, 256, 0, stream>>>(qweight, qscale, qzero, weffT);

    dim3 grid(OFEAT / 64, rows / 64);
    gemm96_kernel<<<grid, 256, 0, stream>>>(xg, weffT, bias, out);
}

// Round 2
// 73.055 us; speedup vs baseline: 2.8384x; 2.8384x over previous
//
#include <hip/hip_runtime.h>
#include <hip/hip_bf16.h>

// EXL2Linear — faithful to the reference's (quirky) unpack indexing:
// only W[:, 0:64] receives quantized codes; W[:, 64:] == qzero broadcast.
// out[r,o] = s0(o) * sum_{j<64} x[r,j]*uq(o,j) + sum_g qzero[o,g]*gsum[r,g] + bias[o]
// Collapsed to a K=96 bf16 MFMA GEMM: xg[rows][96] @ weff[O][96]^T.

constexpr int IFEAT  = 4096;
constexpr int OFEAT  = 4096;
constexpr int GROUPS = 32;   // IFEAT / 128
constexpr int KD     = 96;   // 64 quantized cols + 32 group sums

using short8 = __attribute__((ext_vector_type(8))) short;
using f32x16 = __attribute__((ext_vector_type(16))) float;

static __device__ __forceinline__ unsigned short f2bf(float f) {
    union { float f; unsigned int u; } v; v.f = f;
    unsigned int lsb = (v.u >> 16) & 1;
    v.u += 0x7fff + lsb;           // round-to-nearest-even
    return (unsigned short)(v.u >> 16);
}

// ---------------- Kernel A: per-row first-64 cols (bf16) + 32 group sums (bf16)
__global__ __launch_bounds__(256) void prep_x_kernel(const float* __restrict__ x,
                                                     unsigned short* __restrict__ xg) {
    const int row = blockIdx.x;
    const int t   = threadIdx.x;
    const float4* __restrict__ x4 = (const float4*)(x + (size_t)row * IFEAT);
    unsigned short* __restrict__ xr = xg + (size_t)row * KD;

    #pragma unroll
    for (int i = 0; i < 4; ++i) {
        const float4 v = x4[i * 256 + t];
        float s = v.x + v.y + v.z + v.w;
        // reduce within 32-lane halves (one group = 32 lanes x 4 floats = 128)
        #pragma unroll
        for (int off = 1; off <= 16; off <<= 1) s += __shfl_xor(s, off);
        if ((t & 31) == 0) {
            const int g = i * 8 + (t >> 5);
            xr[64 + g] = f2bf(s);
        }
    }
    if (t < 64) xr[t] = f2bf(x[(size_t)row * IFEAT + t]);
}

// ---------------- Kernel B: build weff[O][96] bf16 (row-major, K contiguous)
__global__ __launch_bounds__(256) void prep_w_kernel(const int* __restrict__ qweight,
                                                     const float* __restrict__ qscale,
                                                     const int* __restrict__ qzero,
                                                     unsigned short* __restrict__ weff) {
    const int o = blockIdx.x * blockDim.x + threadIdx.x;
    if (o >= OFEAT) return;
    const float s0 = qscale[(size_t)o * GROUPS];  // group-0 scale
    const unsigned int* qw = (const unsigned int*)qweight + (size_t)o * (IFEAT / 8);
    unsigned int q[8];
    #pragma unroll
    for (int c = 0; c < 8; ++c) q[c] = qw[c];
    unsigned short* wr = weff + (size_t)o * KD;
    #pragma unroll
    for (int j = 0; j < 64; ++j) {
        const int c = j & 7;
        const int i = j >> 3;
        const float uq = (float)((q[c] >> (i * 4)) & 15u);
        wr[j] = f2bf(uq * s0);
    }
    #pragma unroll
    for (int g = 0; g < GROUPS; ++g) {
        wr[64 + g] = f2bf((float)qzero[(size_t)o * GROUPS + g]);
    }
}

// ---------------- Kernel C: out[rows][OFEAT] = xg @ weff^T + bias via MFMA
// Block = 4 waves = 64x64 tile (2x2 of 32x32 wave tiles). No LDS: fragments
// are direct 16B global loads (xg/weff are L2-resident).
__global__ __launch_bounds__(256) void mfma_gemm_kernel(const unsigned short* __restrict__ xg,
                                                        const unsigned short* __restrict__ weff,
                                                        const float* __restrict__ bias,
                                                        float* __restrict__ out) {
    const int wid  = threadIdx.x >> 6;
    const int lane = threadIdx.x & 63;
    const int r0 = blockIdx.y * 64 + (wid >> 1) * 32;
    const int o0 = blockIdx.x * 64 + (wid & 1) * 32;

    const int l31  = lane & 31;
    const int half = lane >> 5;       // 0 or 1
    const int koff = half * 8;

    const short8* __restrict__ ap =
        (const short8*)(xg + (size_t)(r0 + l31) * KD + koff);
    const short8* __restrict__ bp =
        (const short8*)(weff + (size_t)(o0 + l31) * KD + koff);

    f32x16 acc = {};
    #pragma unroll
    for (int ks = 0; ks < 6; ++ks) {
        const short8 a = ap[ks * 2];   // advance 16 shorts per K-step
        const short8 b = bp[ks * 2];
        acc = __builtin_amdgcn_mfma_f32_32x32x16_bf16(a, b, acc, 0, 0, 0);
    }

    const float bb = bias[o0 + l31];
    #pragma unroll
    for (int i = 0; i < 16; ++i) {
        const int row = (i & 3) + 8 * (i >> 2) + 4 * half;
        out[(size_t)(r0 + row) * OFEAT + o0 + l31] = acc[i] + bb;
    }
}

extern "C" void kernel_launch(void* const* d_in, const int* in_sizes, int n_in,
                              void* d_out, int out_size, void* d_ws, size_t ws_size,
                              hipStream_t stream) {
    const float* x       = (const float*)d_in[0];
    const int*   qweight = (const int*)d_in[1];
    const float* qscale  = (const float*)d_in[2];
    const int*   qzero   = (const int*)d_in[3];
    const float* bias    = (const float*)d_in[4];
    float*       out     = (float*)d_out;

    const int rows = in_sizes[0] / IFEAT;  // B*S = 8192

    unsigned short* xg   = (unsigned short*)d_ws;              // rows*96 bf16
    unsigned short* weff = xg + (size_t)rows * KD;             // O*96 bf16

    prep_x_kernel<<<rows, 256, 0, stream>>>(x, xg);
    prep_w_kernel<<<(OFEAT + 255) / 256, 256, 0, stream>>>(qweight, qscale, qzero, weff);

    dim3 grid(OFEAT / 64, rows / 64);
    mfma_gemm_kernel<<<grid, 256, 0, stream>>>(xg, weff, bias, out);
}

// Round 3
// 59.196 us; speedup vs baseline: 3.5030x; 1.2341x over previous
//
#include <hip/hip_runtime.h>

// EXL2Linear — faithful to the reference's (quirky) unpack indexing:
// only W[:, 0:64] receives quantized codes; W[:, 64:] == qzero broadcast.
// out[r,o] = s0(o) * sum_{j<64} x[r,j]*uq(o,j) + sum_g qzero[o,g]*gsum[r,g] + bias[o]
// Collapsed to a K=96 bf16 MFMA GEMM: xg[rows][96] @ weff[O][96]^T.

constexpr int IFEAT  = 4096;
constexpr int OFEAT  = 4096;
constexpr int GROUPS = 32;   // IFEAT / 128
constexpr int KD     = 96;   // 64 quantized cols + 32 group sums
constexpr int WBLKS  = OFEAT / 256;  // 16 weff-prep blocks

using short8 = __attribute__((ext_vector_type(8))) short;
using f32x16 = __attribute__((ext_vector_type(16))) float;

static __device__ __forceinline__ unsigned short f2bf(float f) {
    union { float f; unsigned int u; } v; v.f = f;
    unsigned int lsb = (v.u >> 16) & 1;
    v.u += 0x7fff + lsb;           // round-to-nearest-even
    return (unsigned short)(v.u >> 16);
}

// ---------------- Fused prep: blocks [0,WBLKS) build weff[O][96];
// blocks [WBLKS, WBLKS+rows) build xg[row][96].
__global__ __launch_bounds__(256) void prep_kernel(const float* __restrict__ x,
                                                   const int* __restrict__ qweight,
                                                   const float* __restrict__ qscale,
                                                   const int* __restrict__ qzero,
                                                   unsigned short* __restrict__ xg,
                                                   unsigned short* __restrict__ weff) {
    const int t = threadIdx.x;
    if (blockIdx.x < WBLKS) {
        // ---- weff rows (dispatched first; tiny)
        const int o = blockIdx.x * 256 + t;
        const float s0 = qscale[(size_t)o * GROUPS];  // group-0 scale
        const unsigned int* qw = (const unsigned int*)qweight + (size_t)o * (IFEAT / 8);
        unsigned int q[8];
        #pragma unroll
        for (int c = 0; c < 8; ++c) q[c] = qw[c];
        unsigned short* wr = weff + (size_t)o * KD;
        #pragma unroll
        for (int j = 0; j < 64; ++j) {
            const int c = j & 7;
            const int i = j >> 3;
            const float uq = (float)((q[c] >> (i * 4)) & 15u);
            wr[j] = f2bf(uq * s0);
        }
        #pragma unroll
        for (int g = 0; g < GROUPS; ++g) {
            wr[64 + g] = f2bf((float)qzero[(size_t)o * GROUPS + g]);
        }
        return;
    }
    // ---- xg row
    const int row = blockIdx.x - WBLKS;
    const float4* __restrict__ x4 = (const float4*)(x + (size_t)row * IFEAT);
    unsigned short* __restrict__ xr = xg + (size_t)row * KD;

    #pragma unroll
    for (int i = 0; i < 4; ++i) {
        const float4 v = x4[i * 256 + t];
        float s = v.x + v.y + v.z + v.w;
        // one group = 32 lanes x 4 floats = 128 contiguous elems
        #pragma unroll
        for (int off = 1; off <= 16; off <<= 1) s += __shfl_xor(s, off);
        if ((t & 31) == 0) {
            const int g = i * 8 + (t >> 5);
            xr[64 + g] = f2bf(s);
        }
    }
    if (t < 64) xr[t] = f2bf(x[(size_t)row * IFEAT + t]);
}

// ---------------- GEMM: out[rows][OFEAT] = xg @ weff^T + bias via MFMA
// Block = 4 waves = 128x128 tile (2x2 waves, each wave 64x64 = 2x2 of 32x32).
// No LDS: fragments are direct 16B global loads (xg/weff are L2-resident).
__global__ __launch_bounds__(256) void mfma_gemm_kernel(const unsigned short* __restrict__ xg,
                                                        const unsigned short* __restrict__ weff,
                                                        const float* __restrict__ bias,
                                                        float* __restrict__ out) {
    const int wid  = threadIdx.x >> 6;
    const int lane = threadIdx.x & 63;
    const int r0 = blockIdx.y * 128 + (wid >> 1) * 64;
    const int o0 = blockIdx.x * 128 + (wid & 1) * 64;

    const int l31  = lane & 31;
    const int half = lane >> 5;       // 0 or 1
    const int koff = half * 8;

    const short8* __restrict__ ap0 = (const short8*)(xg + (size_t)(r0 + l31) * KD + koff);
    const short8* __restrict__ ap1 = (const short8*)(xg + (size_t)(r0 + 32 + l31) * KD + koff);
    const short8* __restrict__ bp0 = (const short8*)(weff + (size_t)(o0 + l31) * KD + koff);
    const short8* __restrict__ bp1 = (const short8*)(weff + (size_t)(o0 + 32 + l31) * KD + koff);

    f32x16 acc00 = {}, acc01 = {}, acc10 = {}, acc11 = {};
    #pragma unroll
    for (int ks = 0; ks < 6; ++ks) {
        const short8 a0 = ap0[ks * 2];   // advance 16 shorts per K-step
        const short8 a1 = ap1[ks * 2];
        const short8 b0 = bp0[ks * 2];
        const short8 b1 = bp1[ks * 2];
        acc00 = __builtin_amdgcn_mfma_f32_32x32x16_bf16(a0, b0, acc00, 0, 0, 0);
        acc01 = __builtin_amdgcn_mfma_f32_32x32x16_bf16(a0, b1, acc01, 0, 0, 0);
        acc10 = __builtin_amdgcn_mfma_f32_32x32x16_bf16(a1, b0, acc10, 0, 0, 0);
        acc11 = __builtin_amdgcn_mfma_f32_32x32x16_bf16(a1, b1, acc11, 0, 0, 0);
    }

    const float bb0 = bias[o0 + l31];
    const float bb1 = bias[o0 + 32 + l31];
    #pragma unroll
    for (int i = 0; i < 16; ++i) {
        const int rr = (i & 3) + 8 * (i >> 2) + 4 * half;
        float* __restrict__ row0 = out + (size_t)(r0 + rr) * OFEAT + o0;
        float* __restrict__ row1 = out + (size_t)(r0 + 32 + rr) * OFEAT + o0;
        row0[l31]      = acc00[i] + bb0;
        row0[32 + l31] = acc01[i] + bb1;
        row1[l31]      = acc10[i] + bb0;
        row1[32 + l31] = acc11[i] + bb1;
    }
}

extern "C" void kernel_launch(void* const* d_in, const int* in_sizes, int n_in,
                              void* d_out, int out_size, void* d_ws, size_t ws_size,
                              hipStream_t stream) {
    const float* x       = (const float*)d_in[0];
    const int*   qweight = (const int*)d_in[1];
    const float* qscale  = (const float*)d_in[2];
    const int*   qzero   = (const int*)d_in[3];
    const float* bias    = (const float*)d_in[4];
    float*       out     = (float*)d_out;

    const int rows = in_sizes[0] / IFEAT;  // B*S = 8192

    unsigned short* xg   = (unsigned short*)d_ws;              // rows*96 bf16
    unsigned short* weff = xg + (size_t)rows * KD;             // O*96 bf16

    prep_kernel<<<rows + WBLKS, 256, 0, stream>>>(x, qweight, qscale, qzero, xg, weff);

    dim3 grid(OFEAT / 128, rows / 128);
    mfma_gemm_kernel<<<grid, 256, 0, stream>>>(xg, weff, bias, out);
}